// Round 2
// baseline (41.355 us; speedup 1.0000x reference)
//
#include <hip/hip_runtime.h>

// Problem constants (from reference):
//   B = 1048576, N = 5, H = 2, CLS = 24, OUT = 5
// Per-element: 5 one-step LSTM cells (h0=c0=0 -> w_hh unused, f-gate unused),
// feats = [h(5x2), others(14)] (24), hidden = relu(feats@w1^T+b1) (24),
// out = sigmoid(hidden@w2^T+b2) (5).

constexpr int Bc   = 1048576;
constexpr int Nc   = 5;
constexpr int Hc   = 2;
constexpr int CLSc = 24;
constexpr int OUTc = 5;
constexpr int OTH  = 14;   // others feature dim

__device__ __forceinline__ float fast_sigmoid(float x) {
    // 1/(1+e^-x); rcp is ~2^-22 rel err, fine vs f32 reference tolerance
    return __builtin_amdgcn_rcpf(1.0f + __expf(-x));
}

__device__ __forceinline__ float fast_tanh(float x) {
    // clamp so exp doesn't overflow (gates here are |x| <~ 2 anyway)
    x = fminf(fmaxf(x, -15.0f), 15.0f);
    float t = __expf(2.0f * x);
    return (t - 1.0f) * __builtin_amdgcn_rcpf(t + 1.0f);
}

__global__ __launch_bounds__(256) void fused_rnn_mlp(
    const float* __restrict__ seqs,    // [N,1,B,H]
    const float* __restrict__ others,  // [1,B,14]
    const float* __restrict__ w_ih,    // [N,8,2]
    const float* __restrict__ b_ih,    // [N,8]
    const float* __restrict__ b_hh,    // [N,8]
    const float* __restrict__ w1,      // [24,24]
    const float* __restrict__ b1,      // [24]
    const float* __restrict__ w2,      // [5,24]
    const float* __restrict__ b2,      // [5]
    float* __restrict__ out)           // [B,5]
{
    __shared__ float s_wih[Nc * 8 * Hc];     // 80
    __shared__ float s_bias[Nc * 8];         // 40 (b_ih + b_hh)
    __shared__ float s_w1[CLSc * CLSc];      // 576
    __shared__ float s_b1[CLSc];             // 24
    __shared__ float s_w2[OUTc * CLSc];      // 120
    __shared__ float s_b2[OUTc];             // 5

    const int t = threadIdx.x;
    if (t < Nc * 8 * Hc) s_wih[t] = w_ih[t];
    if (t < Nc * 8)      s_bias[t] = b_ih[t] + b_hh[t];
    for (int i = t; i < CLSc * CLSc; i += 256) s_w1[i] = w1[i];
    if (t < CLSc)        s_b1[t] = b1[t];
    if (t < OUTc * CLSc) s_w2[t] = w2[t];
    if (t < OUTc)        s_b2[t] = b2[t];
    __syncthreads();

    const int b = blockIdx.x * 256 + t;

    float feats[CLSc];

    // ----- 5 LSTM cells, one timestep, h0=c0=0 -----
#pragma unroll
    for (int n = 0; n < Nc; n++) {
        const float2 x = *reinterpret_cast<const float2*>(
            seqs + ((size_t)n * Bc + b) * Hc);
        const float* w = &s_wih[n * 16];   // [8 gates][2], gate order i,f,g,o
        const float* bi = &s_bias[n * 8];
        float gi0 = fmaf(x.x, w[0],  fmaf(x.y, w[1],  bi[0]));
        float gi1 = fmaf(x.x, w[2],  fmaf(x.y, w[3],  bi[1]));
        float gg0 = fmaf(x.x, w[8],  fmaf(x.y, w[9],  bi[4]));
        float gg1 = fmaf(x.x, w[10], fmaf(x.y, w[11], bi[5]));
        float go0 = fmaf(x.x, w[12], fmaf(x.y, w[13], bi[6]));
        float go1 = fmaf(x.x, w[14], fmaf(x.y, w[15], bi[7]));
        float c0 = fast_sigmoid(gi0) * fast_tanh(gg0);
        float c1 = fast_sigmoid(gi1) * fast_tanh(gg1);
        feats[n * 2 + 0] = fast_sigmoid(go0) * fast_tanh(c0);
        feats[n * 2 + 1] = fast_sigmoid(go1) * fast_tanh(c1);
    }

    // ----- others[b, 0:14] -> feats[10..23] (7 x float2, 8B-aligned) -----
    {
        const float2* op = reinterpret_cast<const float2*>(others + (size_t)b * OTH);
#pragma unroll
        for (int j = 0; j < OTH / 2; j++) {
            float2 v = op[j];
            feats[Nc * Hc + 2 * j + 0] = v.x;
            feats[Nc * Hc + 2 * j + 1] = v.y;
        }
    }

    // ----- hidden = relu(feats @ w1^T + b1) -----
    float hidden[CLSc];
#pragma unroll
    for (int j = 0; j < CLSc; j++) {
        float acc = s_b1[j];
        const float* wr = &s_w1[j * CLSc];
#pragma unroll
        for (int k = 0; k < CLSc; k++) acc = fmaf(feats[k], wr[k], acc);
        hidden[j] = fmaxf(acc, 0.0f);
    }

    // ----- out = sigmoid(hidden @ w2^T + b2) -----
    float* o = out + (size_t)b * OUTc;
#pragma unroll
    for (int q = 0; q < OUTc; q++) {
        float acc = s_b2[q];
        const float* wr = &s_w2[q * CLSc];
#pragma unroll
        for (int k = 0; k < CLSc; k++) acc = fmaf(hidden[k], wr[k], acc);
        o[q] = fast_sigmoid(acc);
    }
}

extern "C" void kernel_launch(void* const* d_in, const int* in_sizes, int n_in,
                              void* d_out, int out_size, void* d_ws, size_t ws_size,
                              hipStream_t stream) {
    const float* seqs   = (const float*)d_in[0];
    const float* others = (const float*)d_in[1];
    const float* w_ih   = (const float*)d_in[2];
    // d_in[3] = w_hh : dead (h0 = 0)
    const float* b_ih   = (const float*)d_in[4];
    const float* b_hh   = (const float*)d_in[5];
    const float* w1     = (const float*)d_in[6];
    const float* b1     = (const float*)d_in[7];
    const float* w2     = (const float*)d_in[8];
    const float* b2     = (const float*)d_in[9];
    float* out = (float*)d_out;

    dim3 grid(Bc / 256), block(256);
    fused_rnn_mlp<<<grid, block, 0, stream>>>(
        seqs, others, w_ih, b_ih, b_hh, w1, b1, w2, b2, out);
}

// Round 3
// 40.678 us; speedup vs baseline: 1.0166x; 1.0166x over previous
//
#include <hip/hip_runtime.h>

// B = 1048576, N = 5, H = 2, CLS = 24, OUT = 5
// h0=c0=0 -> w_hh dead, f-gate dead.
// Round-3 structure: NO LDS. All weights/biases are read with wave-uniform
// compile-time-indexed addresses -> compiler emits s_load into SGPRs
// (scalar cache). This empties the LDS pipe, which round-2 counters showed
// was the bottleneck (750 ds_read_b32/wave, VALUBusy 58%, HBM 17%).

constexpr int Bc   = 1048576;
constexpr int Nc   = 5;
constexpr int Hc   = 2;
constexpr int CLSc = 24;
constexpr int OUTc = 5;
constexpr int OTH  = 14;

__device__ __forceinline__ float fast_sigmoid(float x) {
    return __builtin_amdgcn_rcpf(1.0f + __expf(-x));
}

__device__ __forceinline__ float fast_tanh(float x) {
    x = fminf(fmaxf(x, -15.0f), 15.0f);
    float t = __expf(2.0f * x);
    return (t - 1.0f) * __builtin_amdgcn_rcpf(t + 1.0f);
}

__global__ __launch_bounds__(256) void fused_rnn_mlp(
    const float* __restrict__ seqs,    // [N,1,B,H]
    const float* __restrict__ others,  // [1,B,14]
    const float* __restrict__ w_ih,    // [N,8,2]
    const float* __restrict__ b_ih,    // [N,8]
    const float* __restrict__ b_hh,    // [N,8]
    const float* __restrict__ w1,      // [24,24]
    const float* __restrict__ b1,      // [24]
    const float* __restrict__ w2,      // [5,24]
    const float* __restrict__ b2,      // [5]
    float* __restrict__ out)           // [B,5]
{
    const int b = blockIdx.x * 256 + threadIdx.x;

    float feats[CLSc];

    // ----- 5 LSTM cells, one timestep, h0=c0=0 -----
    // All w_ih/b_* indices are compile-time constants -> uniform s_loads.
#pragma unroll
    for (int n = 0; n < Nc; n++) {
        const float2 x = *reinterpret_cast<const float2*>(
            seqs + ((size_t)n * Bc + b) * Hc);
        const float* w = w_ih + n * 16;          // [8 gates][2], order i,f,g,o
        const float bi0 = b_ih[n * 8 + 0] + b_hh[n * 8 + 0];
        const float bi1 = b_ih[n * 8 + 1] + b_hh[n * 8 + 1];
        const float bg0 = b_ih[n * 8 + 4] + b_hh[n * 8 + 4];
        const float bg1 = b_ih[n * 8 + 5] + b_hh[n * 8 + 5];
        const float bo0 = b_ih[n * 8 + 6] + b_hh[n * 8 + 6];
        const float bo1 = b_ih[n * 8 + 7] + b_hh[n * 8 + 7];
        float gi0 = fmaf(x.x, w[0],  fmaf(x.y, w[1],  bi0));
        float gi1 = fmaf(x.x, w[2],  fmaf(x.y, w[3],  bi1));
        float gg0 = fmaf(x.x, w[8],  fmaf(x.y, w[9],  bg0));
        float gg1 = fmaf(x.x, w[10], fmaf(x.y, w[11], bg1));
        float go0 = fmaf(x.x, w[12], fmaf(x.y, w[13], bo0));
        float go1 = fmaf(x.x, w[14], fmaf(x.y, w[15], bo1));
        float c0 = fast_sigmoid(gi0) * fast_tanh(gg0);
        float c1 = fast_sigmoid(gi1) * fast_tanh(gg1);
        feats[n * 2 + 0] = fast_sigmoid(go0) * fast_tanh(c0);
        feats[n * 2 + 1] = fast_sigmoid(go1) * fast_tanh(c1);
    }

    // ----- others[b, 0:14] -> feats[10..23] -----
    {
        const float2* op = reinterpret_cast<const float2*>(others + (size_t)b * OTH);
#pragma unroll
        for (int j = 0; j < OTH / 2; j++) {
            float2 v = op[j];
            feats[Nc * Hc + 2 * j + 0] = v.x;
            feats[Nc * Hc + 2 * j + 1] = v.y;
        }
    }

    // ----- hidden = relu(feats @ w1^T + b1), weights via uniform s_load -----
    float hidden[CLSc];
#pragma unroll
    for (int j = 0; j < CLSc; j++) {
        float acc = b1[j];
        const float* wr = w1 + j * CLSc;
#pragma unroll
        for (int k = 0; k < CLSc; k++) acc = fmaf(feats[k], wr[k], acc);
        hidden[j] = fmaxf(acc, 0.0f);
    }

    // ----- out = sigmoid(hidden @ w2^T + b2) -----
    float* o = out + (size_t)b * OUTc;
#pragma unroll
    for (int q = 0; q < OUTc; q++) {
        float acc = b2[q];
        const float* wr = w2 + q * CLSc;
#pragma unroll
        for (int k = 0; k < CLSc; k++) acc = fmaf(hidden[k], wr[k], acc);
        o[q] = fast_sigmoid(acc);
    }
}

extern "C" void kernel_launch(void* const* d_in, const int* in_sizes, int n_in,
                              void* d_out, int out_size, void* d_ws, size_t ws_size,
                              hipStream_t stream) {
    const float* seqs   = (const float*)d_in[0];
    const float* others = (const float*)d_in[1];
    const float* w_ih   = (const float*)d_in[2];
    // d_in[3] = w_hh : dead (h0 = 0)
    const float* b_ih   = (const float*)d_in[4];
    const float* b_hh   = (const float*)d_in[5];
    const float* w1     = (const float*)d_in[6];
    const float* b1     = (const float*)d_in[7];
    const float* w2     = (const float*)d_in[8];
    const float* b2     = (const float*)d_in[9];
    float* out = (float*)d_out;

    dim3 grid(Bc / 256), block(256);
    fused_rnn_mlp<<<grid, block, 0, stream>>>(
        seqs, others, w_ih, b_ih, b_hh, w1, b1, w2, b2, out);
}